// Round 2
// baseline (649.457 us; speedup 1.0000x reference)
//
#include <hip/hip_runtime.h>
#include <hip/hip_bf16.h>

typedef __bf16 bf16_t;
typedef bf16_t bf16x8 __attribute__((ext_vector_type(8)));
typedef float floatx4 __attribute__((ext_vector_type(4)));

// ---------------------------------------------------------------------------
// One-time weight convert fp32 -> bf16 into workspace.
// wb layout: [0 .. 196607] = w_qkv (768x256), [196608 .. 262143] = w_proj.
// ---------------------------------------------------------------------------
__global__ __launch_bounds__(256) void wconv_kernel(
    const float* __restrict__ w_qkv, const float* __restrict__ w_proj,
    bf16_t* __restrict__ wb)
{
  int idx4 = (blockIdx.x * 256 + threadIdx.x) * 4;
  const float* src = (idx4 < 196608) ? (w_qkv + idx4) : (w_proj + (idx4 - 196608));
  float4 f = *(const float4*)src;
  bf16_t o[4] = {(bf16_t)f.x, (bf16_t)f.y, (bf16_t)f.z, (bf16_t)f.w};
  *(uint2*)(wb + idx4) = *(const uint2*)o;
}

// ---------------------------------------------------------------------------
// Kernel 1: per-token attention on contiguous 32-token tiles.
// The attention einsums contract q,k,v at the SAME token s (head-mix), so
// qkv + softmax + PV are strictly per-token. Writes the attention output
// ("pre", layout c = h*32+d) as fp32 into the out buffer in token order
// (fully coalesced). The window scramble + projection happen in kernel 2.
//
// 512 thr = 8 waves. LDS 50.7 KB -> 3 blocks/CU.
// P0 stage X -> P1 QK gemm (8 waves, cols 0..511) -> P2 {waves 0-3: 8x8
// head-mix softmax | waves 4-7: V gemm} -> V to LDS -> P3 PV + global store.
// ---------------------------------------------------------------------------
#define XS_S 272   // row stride (bf16) for Xs: 544B, 16B-aligned
#define QK_S 520   // row stride (bf16) for QK/V: 1040B, 16B-aligned

__global__ __launch_bounds__(512, 6) void attn_kernel(
    const float* __restrict__ x,
    const bf16_t* __restrict__ wb,
    float* __restrict__ out)
{
  __shared__ __align__(16) bf16_t Xs[32][XS_S];   // 17.0 KB  X tile
  __shared__ __align__(16) bf16_t QK[32][QK_S];   // 32.5 KB  Q|K, later V in 0..255

  const int tid = threadIdx.x;
  const int wave = tid >> 6, lane = tid & 63, quad = lane >> 4, l16 = lane & 15;
  const long base = (long)blockIdx.x * 32;
  const float scale = 0.17677669529663687f;       // 32^-0.5

  // ---- P0: stage X: 32x256 fp32 -> bf16 LDS, fully coalesced ----
  const float* xb = x + base * 256;
#pragma unroll
  for (int it = 0; it < 2; ++it) {
    int idx = tid + it * 512;                 // 0..1023 groups of 8 floats
    int s = idx >> 5, g = (idx & 31) * 8;
    const float* p = xb + s * 256 + g;
    float4 f0 = ((const float4*)p)[0];
    float4 f1 = ((const float4*)p)[1];
    bf16_t t8[8] = {(bf16_t)f0.x, (bf16_t)f0.y, (bf16_t)f0.z, (bf16_t)f0.w,
                    (bf16_t)f1.x, (bf16_t)f1.y, (bf16_t)f1.z, (bf16_t)f1.w};
    *(uint4*)(&Xs[s][g]) = *(const uint4*)t8;
  }
  __syncthreads();

  // ---- P1: QK gemm: [32x512] = X @ Wqk^T ----
  {
    floatx4 acc[8] = {};
    const int mt = wave >> 2;
    const int cb = (wave & 3) * 128;
    const bf16_t* wq = wb + (long)cb * 256;
#pragma unroll
    for (int k = 0; k < 8; ++k) {
      bf16x8 a = *(const bf16x8*)(&Xs[mt * 16 + l16][k * 32 + quad * 8]);
#pragma unroll
      for (int j = 0; j < 8; ++j) {
        bf16x8 b = *(const bf16x8*)(wq + (j * 16 + l16) * 256 + k * 32 + quad * 8);
        acc[j] = __builtin_amdgcn_mfma_f32_16x16x32_bf16(a, b, acc[j], 0, 0, 0);
      }
    }
#pragma unroll
    for (int j = 0; j < 8; ++j)
#pragma unroll
      for (int r = 0; r < 4; ++r)
        QK[mt * 16 + quad * 4 + r][cb + j * 16 + l16] = (bf16_t)acc[j][r];
  }
  __syncthreads();

  // ---- P2: waves 0-3: per-token 8x8 head-mix scores + softmax (VALU)
  //          waves 4-7: V gemm [32x256] = X @ Wv^T            (MFMA) ----
  float p_[8];         // probs, persist to PV (waves 0-3)
  floatx4 vacc[8];     // V gemm acc (waves 4-7)
  if (wave < 4) {
    const int t = tid >> 3, h = tid & 7;     // 256 tasks = 32 tok x 8 heads
    float sc[8];
#pragma unroll
    for (int e = 0; e < 8; ++e) sc[e] = 0.f;
#pragma unroll
    for (int u = 0; u < 4; ++u) {
      bf16x8 qv = *(const bf16x8*)(&QK[t][h * 32 + u * 8]);
      float qf[8];
#pragma unroll
      for (int d = 0; d < 8; ++d) qf[d] = (float)qv[d];
#pragma unroll
      for (int e = 0; e < 8; ++e) {
        bf16x8 kv = *(const bf16x8*)(&QK[t][256 + e * 32 + u * 8]);
#pragma unroll
        for (int d = 0; d < 8; ++d) sc[e] += qf[d] * (float)kv[d];
      }
    }
    float mx = -INFINITY;
#pragma unroll
    for (int e = 0; e < 8; ++e) { sc[e] *= scale; mx = fmaxf(mx, sc[e]); }
    float sum = 0.f;
#pragma unroll
    for (int e = 0; e < 8; ++e) { p_[e] = __expf(sc[e] - mx); sum += p_[e]; }
    float rs = 1.0f / sum;
#pragma unroll
    for (int e = 0; e < 8; ++e) p_[e] *= rs;
  } else {
    const int u = wave - 4;
    const int mt = u >> 1;
    const int cb = (u & 1) * 128;
    const bf16_t* wv = wb + (long)(512 + cb) * 256;
#pragma unroll
    for (int j = 0; j < 8; ++j) vacc[j] = (floatx4){0.f, 0.f, 0.f, 0.f};
#pragma unroll
    for (int k = 0; k < 8; ++k) {
      bf16x8 a = *(const bf16x8*)(&Xs[mt * 16 + l16][k * 32 + quad * 8]);
#pragma unroll
      for (int j = 0; j < 8; ++j) {
        bf16x8 b = *(const bf16x8*)(wv + (j * 16 + l16) * 256 + k * 32 + quad * 8);
        vacc[j] = __builtin_amdgcn_mfma_f32_16x16x32_bf16(a, b, vacc[j], 0, 0, 0);
      }
    }
  }
  __syncthreads();   // q,k LDS reads done; V acc ready

  if (wave >= 4) {   // V overwrites cols 0..255 of QK
    const int u = wave - 4;
    const int mt = u >> 1;
    const int cb = (u & 1) * 128;
#pragma unroll
    for (int j = 0; j < 8; ++j)
#pragma unroll
      for (int r = 0; r < 4; ++r)
        QK[mt * 16 + quad * 4 + r][cb + j * 16 + l16] = (bf16_t)vacc[j][r];
  }
  __syncthreads();   // V ready

  // ---- P3: PV (waves 0-3): pre[t, h*32+d] = sum_e p[e]*v[t, e*32+d],
  //          then store fp32 to out[base+t][h*32..] (coalesced) ----
  if (wave < 4) {
    const int t = tid >> 3, h = tid & 7;
    float pre[32];
#pragma unroll
    for (int i = 0; i < 32; ++i) pre[i] = 0.f;
#pragma unroll
    for (int e = 0; e < 8; ++e) {
      float pe = p_[e];
#pragma unroll
      for (int u = 0; u < 4; ++u) {
        bf16x8 vv = *(const bf16x8*)(&QK[t][e * 32 + u * 8]);
#pragma unroll
        for (int d = 0; d < 8; ++d) pre[u * 8 + d] += pe * (float)vv[d];
      }
    }
    float* op = out + (base + t) * 256 + h * 32;
#pragma unroll
    for (int u = 0; u < 8; ++u) {
      float4 f = {pre[u * 4], pre[u * 4 + 1], pre[u * 4 + 2], pre[u * 4 + 3]};
      ((float4*)op)[u] = f;
    }
  }
}

// ---------------------------------------------------------------------------
// Kernel 2: per-window scramble + projection, in-place on out.
// Reference: out.swapaxes(1,2).reshape(-1,49,256): within each window,
// flat = h*1568 + s*32 + d maps to scram row s'=flat>>8, chan c'=flat&255.
// Block = 1 window. Stage: gather the window's 49 pre rows (fp32, from out),
// convert bf16, write into LDS at the SCRAMBLED address. Then proj gemm
// (M=49 pad 64, N=256, K=256) and store to out rows trow[s'] + bias.
// All of a window's rows are read to LDS before any store; windows own
// disjoint row sets -> in-place is race-free.
// ---------------------------------------------------------------------------
#define SC_S 264   // row stride (bf16): 528B, 16B-aligned

__global__ __launch_bounds__(512, 8) void proj_kernel(
    const bf16_t* __restrict__ wb,
    const float* __restrict__ b_proj,
    float* out)
{
  __shared__ __align__(16) bf16_t Sc[49][SC_S];   // 25.9 KB scrambled pre
  __shared__ int trow[49];

  const int n = blockIdx.x;              // window id 0..2047
  const int b = n >> 6, wh = (n >> 3) & 7, ww = n & 7;
  const int tid = threadIdx.x;
  const int wave = tid >> 6, lane = tid & 63, quad = lane >> 4, l16 = lane & 15;

  if (tid < 49) {
    int i = tid / 7, j = tid % 7;
    trow[tid] = b * 3136 + (wh * 7 + i) * 56 + ww * 7 + j;
  }
  __syncthreads();

  // ---- stage + scramble: 49 rows x 32 chunks of 8 floats ----
  for (int idx = tid; idx < 49 * 32; idx += 512) {
    int s = idx >> 5, g8 = idx & 31;
    const float* p = out + (long)trow[s] * 256 + g8 * 8;
    float4 f0 = ((const float4*)p)[0];
    float4 f1 = ((const float4*)p)[1];
    bf16_t t8[8] = {(bf16_t)f0.x, (bf16_t)f0.y, (bf16_t)f0.z, (bf16_t)f0.w,
                    (bf16_t)f1.x, (bf16_t)f1.y, (bf16_t)f1.z, (bf16_t)f1.w};
    int flat = (g8 >> 2) * 1568 + s * 32 + (g8 & 3) * 8;   // h*1568 + s*32 + d
    *(uint4*)(&Sc[flat >> 8][flat & 255]) = *(const uint4*)t8;
  }
  __syncthreads();

  // ---- proj gemm: out(49x256) = Sc @ Wp^T + bias ----
  {
    floatx4 acc[8] = {};
    const int mt = wave >> 1;            // 4 M-tiles of 16
    const int cb = (wave & 1) * 128;     // 2 N-halves
    const bf16_t* wp = wb + 196608 + (long)cb * 256;
#pragma unroll
    for (int k = 0; k < 8; ++k) {
      int mr = mt * 16 + l16; if (mr > 48) mr = 48;
      bf16x8 a = *(const bf16x8*)(&Sc[mr][k * 32 + quad * 8]);
#pragma unroll
      for (int j = 0; j < 8; ++j) {
        bf16x8 bf = *(const bf16x8*)(wp + (j * 16 + l16) * 256 + k * 32 + quad * 8);
        acc[j] = __builtin_amdgcn_mfma_f32_16x16x32_bf16(a, bf, acc[j], 0, 0, 0);
      }
    }
#pragma unroll
    for (int j = 0; j < 8; ++j) {
      int col = cb + j * 16 + l16;
      float bv = b_proj[col];
#pragma unroll
      for (int r = 0; r < 4; ++r) {
        int m = mt * 16 + quad * 4 + r;
        if (m < 49) out[(long)trow[m] * 256 + col] = acc[j][r] + bv;
      }
    }
  }
}

// ---------------------------------------------------------------------------
extern "C" void kernel_launch(void* const* d_in, const int* in_sizes, int n_in,
                              void* d_out, int out_size, void* d_ws, size_t ws_size,
                              hipStream_t stream) {
  (void)in_sizes; (void)n_in; (void)out_size; (void)ws_size;
  const float* x      = (const float*)d_in[0];
  const float* w_qkv  = (const float*)d_in[1];
  const float* w_proj = (const float*)d_in[2];
  const float* b_proj = (const float*)d_in[3];
  float* out = (float*)d_out;
  bf16_t* wb = (bf16_t*)d_ws;   // 262144 bf16 = 512 KB

  wconv_kernel<<<dim3(256), 256, 0, stream>>>(w_qkv, w_proj, wb);
  attn_kernel<<<dim3(3136), 512, 0, stream>>>(x, wb, out);
  proj_kernel<<<dim3(2048), 512, 0, stream>>>(wb, b_proj, out);
}

// Round 3
// 506.849 us; speedup vs baseline: 1.2814x; 1.2814x over previous
//
#include <hip/hip_runtime.h>
#include <hip/hip_bf16.h>

typedef __bf16 bf16_t;
typedef bf16_t bf16x8 __attribute__((ext_vector_type(8)));
typedef float floatx4 __attribute__((ext_vector_type(4)));

// ---------------------------------------------------------------------------
// One-time weight convert fp32 -> bf16 into workspace.
// wb layout: [0 .. 196607] = w_qkv (768x256), [196608 .. 262143] = w_proj.
// ---------------------------------------------------------------------------
__global__ __launch_bounds__(256) void wconv_kernel(
    const float* __restrict__ w_qkv, const float* __restrict__ w_proj,
    bf16_t* __restrict__ wb)
{
  int idx4 = (blockIdx.x * 256 + threadIdx.x) * 4;
  const float* src = (idx4 < 196608) ? (w_qkv + idx4) : (w_proj + (idx4 - 196608));
  float4 f = *(const float4*)src;
  bf16_t o[4] = {(bf16_t)f.x, (bf16_t)f.y, (bf16_t)f.z, (bf16_t)f.w};
  *(uint2*)(wb + idx4) = *(const uint2*)o;
}

#define MFMA16(a, b, c) __builtin_amdgcn_mfma_f32_16x16x32_bf16((a), (b), (c), 0, 0, 0)

// ---------------------------------------------------------------------------
// Kernel 1: per-token attention on contiguous 32-token tiles.
// Latency-hiding restructure: all weight B-panels preloaded to registers in
// one burst (QK panel issued BEFORE the staging barrier so its L2 latency
// hides under X staging); softmax/PV LDS reads batched into register bursts.
// Wave->tile map dedup'd: wave w owns 64 distinct output cols (no dup loads).
// 512 thr = 8 waves. LDS 50.7 KB -> 3 blocks/CU.
// ---------------------------------------------------------------------------
#define XS_S 272   // row stride (bf16) for Xs: 544B, 16B-aligned
#define QK_S 520   // row stride (bf16) for QK/V: 1040B, 16B-aligned

__global__ __launch_bounds__(512, 6) void attn_kernel(
    const float* __restrict__ x,
    const bf16_t* __restrict__ wb,
    float* __restrict__ outf,
    bf16_t* __restrict__ preb)          // non-null: write pre as bf16 here
{
  __shared__ __align__(16) bf16_t Xs[32][XS_S];   // 17.0 KB  X tile
  __shared__ __align__(16) bf16_t QK[32][QK_S];   // 32.5 KB  Q|K, later V in 0..255

  const int tid = threadIdx.x;
  const int wave = tid >> 6, lane = tid & 63, quad = lane >> 4, l16 = lane & 15;
  const long base = (long)blockIdx.x * 32;
  const float scale = 0.17677669529663687f;       // 32^-0.5

  // ---- P0a: issue X loads (oldest in VMEM queue) ----
  const float* xb = x + base * 256;
  float4 xf[2][2];
  int xs_[2], xg_[2];
#pragma unroll
  for (int it = 0; it < 2; ++it) {
    int idx = tid + it * 512;                 // 0..1023 groups of 8 floats
    xs_[it] = idx >> 5; xg_[it] = (idx & 31) * 8;
    const float* p = xb + xs_[it] * 256 + xg_[it];
    xf[it][0] = ((const float4*)p)[0];
    xf[it][1] = ((const float4*)p)[1];
  }

  // ---- P0b: issue QK weight panel preload (hides under staging) ----
  // wave w owns output cols [w*64, w*64+64): j in 0..3 16-col frags.
  const bf16_t* wq = wb + (long)(wave * 64) * 256;
  bf16x8 Bq[8][4];
#pragma unroll
  for (int k = 0; k < 8; ++k)
#pragma unroll
    for (int j = 0; j < 4; ++j)
      Bq[k][j] = *(const bf16x8*)(wq + (j * 16 + l16) * 256 + k * 32 + quad * 8);

  // ---- P0c: convert + write X to LDS ----
#pragma unroll
  for (int it = 0; it < 2; ++it) {
    float4 f0 = xf[it][0], f1 = xf[it][1];
    bf16_t t8[8] = {(bf16_t)f0.x, (bf16_t)f0.y, (bf16_t)f0.z, (bf16_t)f0.w,
                    (bf16_t)f1.x, (bf16_t)f1.y, (bf16_t)f1.z, (bf16_t)f1.w};
    *(uint4*)(&Xs[xs_[it]][xg_[it]]) = *(const uint4*)t8;
  }
  __syncthreads();

  // ---- P1: QK gemm [32x512] = X @ Wqk^T, fully register-resident ----
  {
    bf16x8 A[8][2];
#pragma unroll
    for (int k = 0; k < 8; ++k)
#pragma unroll
      for (int i = 0; i < 2; ++i)
        A[k][i] = *(const bf16x8*)(&Xs[i * 16 + l16][k * 32 + quad * 8]);
    floatx4 acc[2][4] = {};
#pragma unroll
    for (int k = 0; k < 8; ++k)
#pragma unroll
      for (int j = 0; j < 4; ++j)
#pragma unroll
        for (int i = 0; i < 2; ++i)
          acc[i][j] = MFMA16(A[k][i], Bq[k][j], acc[i][j]);
#pragma unroll
    for (int i = 0; i < 2; ++i)
#pragma unroll
      for (int j = 0; j < 4; ++j)
#pragma unroll
        for (int r = 0; r < 4; ++r)
          QK[i * 16 + quad * 4 + r][wave * 64 + j * 16 + l16] = (bf16_t)acc[i][j][r];
  }
  __syncthreads();

  // ---- P2: waves 0-3: per-token 8x8 head-mix softmax (batched LDS reads)
  //          waves 4-7: V gemm [32x256] = X @ Wv^T (preloaded B) ----
  float p_[8];          // probs (waves 0-3)
  floatx4 vacc[2][4];   // V acc (waves 4-7)
  if (wave < 4) {
    const int t = tid >> 3, h = tid & 7;     // 256 tasks = 32 tok x 8 heads
    bf16x8 qv[4], kv[8][4];
#pragma unroll
    for (int u = 0; u < 4; ++u) qv[u] = *(const bf16x8*)(&QK[t][h * 32 + u * 8]);
#pragma unroll
    for (int e = 0; e < 8; ++e)
#pragma unroll
      for (int u = 0; u < 4; ++u)
        kv[e][u] = *(const bf16x8*)(&QK[t][256 + e * 32 + u * 8]);
    float qf[32];
#pragma unroll
    for (int u = 0; u < 4; ++u)
#pragma unroll
      for (int d = 0; d < 8; ++d) qf[u * 8 + d] = (float)qv[u][d];
    float sc[8];
#pragma unroll
    for (int e = 0; e < 8; ++e) {
      float a = 0.f;
#pragma unroll
      for (int u = 0; u < 4; ++u)
#pragma unroll
        for (int d = 0; d < 8; ++d) a += qf[u * 8 + d] * (float)kv[e][u][d];
      sc[e] = a;
    }
    float mx = -INFINITY;
#pragma unroll
    for (int e = 0; e < 8; ++e) { sc[e] *= scale; mx = fmaxf(mx, sc[e]); }
    float sum = 0.f;
#pragma unroll
    for (int e = 0; e < 8; ++e) { p_[e] = __expf(sc[e] - mx); sum += p_[e]; }
    float rs = 1.0f / sum;
#pragma unroll
    for (int e = 0; e < 8; ++e) p_[e] *= rs;
  } else {
    const int u = wave - 4;                  // owns V cols [u*64, u*64+64)
    const bf16_t* wv = wb + (long)(512 + u * 64) * 256;
    bf16x8 Bv[8][4];
#pragma unroll
    for (int k = 0; k < 8; ++k)
#pragma unroll
      for (int j = 0; j < 4; ++j)
        Bv[k][j] = *(const bf16x8*)(wv + (j * 16 + l16) * 256 + k * 32 + quad * 8);
    bf16x8 A[8][2];
#pragma unroll
    for (int k = 0; k < 8; ++k)
#pragma unroll
      for (int i = 0; i < 2; ++i)
        A[k][i] = *(const bf16x8*)(&Xs[i * 16 + l16][k * 32 + quad * 8]);
#pragma unroll
    for (int i = 0; i < 2; ++i)
#pragma unroll
      for (int j = 0; j < 4; ++j) vacc[i][j] = (floatx4){0.f, 0.f, 0.f, 0.f};
#pragma unroll
    for (int k = 0; k < 8; ++k)
#pragma unroll
      for (int j = 0; j < 4; ++j)
#pragma unroll
        for (int i = 0; i < 2; ++i)
          vacc[i][j] = MFMA16(A[k][i], Bv[k][j], vacc[i][j]);
  }
  __syncthreads();   // q,k LDS reads done; V acc ready

  if (wave >= 4) {   // V overwrites cols 0..255 of QK
    const int u = wave - 4;
#pragma unroll
    for (int i = 0; i < 2; ++i)
#pragma unroll
      for (int j = 0; j < 4; ++j)
#pragma unroll
        for (int r = 0; r < 4; ++r)
          QK[i * 16 + quad * 4 + r][u * 64 + j * 16 + l16] = (bf16_t)vacc[i][j][r];
  }
  __syncthreads();   // V ready

  // ---- P3: PV (waves 0-3), batched V reads; store pre ----
  if (wave < 4) {
    const int t = tid >> 3, h = tid & 7;
    bf16x8 vv[8][4];
#pragma unroll
    for (int e = 0; e < 8; ++e)
#pragma unroll
      for (int u = 0; u < 4; ++u)
        vv[e][u] = *(const bf16x8*)(&QK[t][e * 32 + u * 8]);
    float pre[32];
#pragma unroll
    for (int i = 0; i < 32; ++i) pre[i] = 0.f;
#pragma unroll
    for (int e = 0; e < 8; ++e) {
      float pe = p_[e];
#pragma unroll
      for (int u = 0; u < 4; ++u)
#pragma unroll
        for (int d = 0; d < 8; ++d) pre[u * 8 + d] += pe * (float)vv[e][u][d];
    }
    if (preb) {
      bf16_t* op = preb + (base + t) * 256 + h * 32;
#pragma unroll
      for (int u = 0; u < 4; ++u) {
        bf16_t t8[8];
#pragma unroll
        for (int d = 0; d < 8; ++d) t8[d] = (bf16_t)pre[u * 8 + d];
        *(uint4*)(op + u * 8) = *(const uint4*)t8;
      }
    } else {
      float* op = outf + (base + t) * 256 + h * 32;
#pragma unroll
      for (int u = 0; u < 8; ++u) {
        float4 f = {pre[u * 4], pre[u * 4 + 1], pre[u * 4 + 2], pre[u * 4 + 3]};
        ((float4*)op)[u] = f;
      }
    }
  }
}

// ---------------------------------------------------------------------------
// Kernel 2: per-window scramble + projection.
// flat = h*1568 + s*32 + d -> scram row flat>>8, chan flat&255 (within window).
// B panel preloaded to regs BEFORE staging (latency hidden under the gather);
// wave w owns 32 distinct output cols (no duplicate weight loads).
// Reads pre from preb (bf16) if non-null, else fp32 from out (in-place safe:
// all reads -> LDS before any store; windows own disjoint rows).
// ---------------------------------------------------------------------------
#define SC_S 264   // row stride (bf16): 528B, 16B-aligned

__global__ __launch_bounds__(512, 6) void proj_kernel(
    const bf16_t* __restrict__ wb,
    const float* __restrict__ b_proj,
    float* out,
    const bf16_t* __restrict__ preb)
{
  __shared__ __align__(16) bf16_t Sc[49][SC_S];   // 25.9 KB scrambled pre
  __shared__ int trow[49];

  const int n = blockIdx.x;              // window id 0..2047
  const int b = n >> 6, wh = (n >> 3) & 7, ww = n & 7;
  const int tid = threadIdx.x;
  const int wave = tid >> 6, lane = tid & 63, quad = lane >> 4, l16 = lane & 15;

  // ---- B panel preload: wave w owns cols [w*32, w*32+32), j in {0,1} ----
  const bf16_t* wp = wb + 196608 + (long)(wave * 32) * 256;
  bf16x8 B[8][2];
#pragma unroll
  for (int k = 0; k < 8; ++k)
#pragma unroll
    for (int j = 0; j < 2; ++j)
      B[k][j] = *(const bf16x8*)(wp + (j * 16 + l16) * 256 + k * 32 + quad * 8);
  float bv[2];
#pragma unroll
  for (int j = 0; j < 2; ++j) bv[j] = b_proj[wave * 32 + j * 16 + l16];

  if (tid < 49) {
    int i = tid / 7, j = tid % 7;
    trow[tid] = b * 3136 + (wh * 7 + i) * 56 + ww * 7 + j;
  }
  __syncthreads();

  // ---- stage + scramble: 49 rows x 32 chunks of 8 values ----
  if (preb) {
    for (int idx = tid; idx < 49 * 32; idx += 512) {
      int s = idx >> 5, g8 = idx & 31;
      bf16x8 v = *(const bf16x8*)(preb + (long)trow[s] * 256 + g8 * 8);
      int flat = (g8 >> 2) * 1568 + s * 32 + (g8 & 3) * 8;   // h*1568 + s*32 + d
      *(bf16x8*)(&Sc[flat >> 8][flat & 255]) = v;
    }
  } else {
    for (int idx = tid; idx < 49 * 32; idx += 512) {
      int s = idx >> 5, g8 = idx & 31;
      const float* p = out + (long)trow[s] * 256 + g8 * 8;
      float4 f0 = ((const float4*)p)[0];
      float4 f1 = ((const float4*)p)[1];
      bf16_t t8[8] = {(bf16_t)f0.x, (bf16_t)f0.y, (bf16_t)f0.z, (bf16_t)f0.w,
                      (bf16_t)f1.x, (bf16_t)f1.y, (bf16_t)f1.z, (bf16_t)f1.w};
      int flat = (g8 >> 2) * 1568 + s * 32 + (g8 & 3) * 8;
      *(uint4*)(&Sc[flat >> 8][flat & 255]) = *(const uint4*)t8;
    }
  }
  __syncthreads();

  // ---- proj gemm: out(49x256) = Sc @ Wp^T + bias ----
  {
    bf16x8 A[8][4];
#pragma unroll
    for (int k = 0; k < 8; ++k)
#pragma unroll
      for (int i = 0; i < 4; ++i) {
        int mr = i * 16 + l16; if (mr > 48) mr = 48;
        A[k][i] = *(const bf16x8*)(&Sc[mr][k * 32 + quad * 8]);
      }
    floatx4 acc[4][2] = {};
#pragma unroll
    for (int k = 0; k < 8; ++k)
#pragma unroll
      for (int i = 0; i < 4; ++i)
#pragma unroll
        for (int j = 0; j < 2; ++j)
          acc[i][j] = MFMA16(A[k][i], B[k][j], acc[i][j]);
#pragma unroll
    for (int j = 0; j < 2; ++j) {
      int col = wave * 32 + j * 16 + l16;
#pragma unroll
      for (int i = 0; i < 4; ++i)
#pragma unroll
        for (int r = 0; r < 4; ++r) {
          int m = i * 16 + quad * 4 + r;
          if (m < 49) out[(long)trow[m] * 256 + col] = acc[i][j][r] + bv[j];
        }
    }
  }
}

// ---------------------------------------------------------------------------
extern "C" void kernel_launch(void* const* d_in, const int* in_sizes, int n_in,
                              void* d_out, int out_size, void* d_ws, size_t ws_size,
                              hipStream_t stream) {
  (void)in_sizes; (void)n_in; (void)out_size;
  const float* x      = (const float*)d_in[0];
  const float* w_qkv  = (const float*)d_in[1];
  const float* w_proj = (const float*)d_in[2];
  const float* b_proj = (const float*)d_in[3];
  float* out = (float*)d_out;
  bf16_t* wb = (bf16_t*)d_ws;   // 262144 bf16 = 512 KB

  // bf16 pre buffer (100352*256*2 = 51.4 MB) if workspace allows
  bf16_t* preb = nullptr;
  if (ws_size >= (size_t)524288 + 51380224) preb = wb + 262144;

  wconv_kernel<<<dim3(256), 256, 0, stream>>>(w_qkv, w_proj, wb);
  attn_kernel<<<dim3(3136), 512, 0, stream>>>(x, wb, out, preb);
  proj_kernel<<<dim3(2048), 512, 0, stream>>>(wb, b_proj, out, preb);
}

// Round 4
// 352.660 us; speedup vs baseline: 1.8416x; 1.4372x over previous
//
#include <hip/hip_runtime.h>
#include <hip/hip_bf16.h>

typedef __bf16 bf16_t;
typedef bf16_t bf16x8 __attribute__((ext_vector_type(8)));
typedef float floatx4 __attribute__((ext_vector_type(4)));

// ---------------------------------------------------------------------------
// One-time weight convert fp32 -> bf16 into workspace.
// wb layout: [0 .. 196607] = w_qkv (768x256), [196608 .. 262143] = w_proj.
// ---------------------------------------------------------------------------
__global__ __launch_bounds__(256) void wconv_kernel(
    const float* __restrict__ w_qkv, const float* __restrict__ w_proj,
    bf16_t* __restrict__ wb)
{
  int idx4 = (blockIdx.x * 256 + threadIdx.x) * 4;
  const float* src = (idx4 < 196608) ? (w_qkv + idx4) : (w_proj + (idx4 - 196608));
  float4 f = *(const float4*)src;
  bf16_t o[4] = {(bf16_t)f.x, (bf16_t)f.y, (bf16_t)f.z, (bf16_t)f.w};
  *(uint2*)(wb + idx4) = *(const uint2*)o;
}

#define MFMA16(a, b, c) __builtin_amdgcn_mfma_f32_16x16x32_bf16((a), (b), (c), 0, 0, 0)

// ---------------------------------------------------------------------------
// Kernel 1: per-token attention on contiguous 32-token tiles.
// Register-budgeted pipeline (VGPR cap 128 via launch_bounds(512,4)):
//  - GEMM B-fragments double-buffered one k-step ahead (32 regs in flight)
//  - softmax/PV LDS reads batched in e-halves (64-reg bursts)
// Wave w owns 64 distinct output cols (no duplicate weight loads).
// LDS 50.7 KB -> 2 blocks/CU at 4 waves/EU.
// ---------------------------------------------------------------------------
#define XS_S 272   // row stride (bf16) for Xs: 544B, 16B-aligned
#define QK_S 520   // row stride (bf16) for QK/V: 1040B, 16B-aligned

__global__ __launch_bounds__(512, 4) void attn_kernel(
    const float* __restrict__ x,
    const bf16_t* __restrict__ wb,
    float* __restrict__ outf,
    bf16_t* __restrict__ preb)          // non-null: write pre as bf16 here
{
  __shared__ __align__(16) bf16_t Xs[32][XS_S];   // 17.0 KB  X tile
  __shared__ __align__(16) bf16_t QK[32][QK_S];   // 32.5 KB  Q|K, later V in 0..255

  const int tid = threadIdx.x;
  const int wave = tid >> 6, lane = tid & 63, quad = lane >> 4, l16 = lane & 15;
  const long base = (long)blockIdx.x * 32;
  const float scale = 0.17677669529663687f;       // 32^-0.5

  // ---- P0: stage X: 32x256 fp32 -> bf16 LDS, fully coalesced ----
  const float* xb = x + base * 256;
#pragma unroll
  for (int it = 0; it < 2; ++it) {
    int idx = tid + it * 512;                 // 0..1023 groups of 8 floats
    int s = idx >> 5, g = (idx & 31) * 8;
    const float* p = xb + s * 256 + g;
    float4 f0 = ((const float4*)p)[0];
    float4 f1 = ((const float4*)p)[1];
    bf16_t t8[8] = {(bf16_t)f0.x, (bf16_t)f0.y, (bf16_t)f0.z, (bf16_t)f0.w,
                    (bf16_t)f1.x, (bf16_t)f1.y, (bf16_t)f1.z, (bf16_t)f1.w};
    *(uint4*)(&Xs[s][g]) = *(const uint4*)t8;
  }
  __syncthreads();

  // ---- P1: QK gemm [32x512] = X @ Wqk^T, k-pipelined B loads ----
  {
    const bf16_t* wq = wb + (long)(wave * 64) * 256;
    floatx4 acc[2][4] = {};
    bf16x8 Ba[4], Bb[4];
    auto loadB = [&](bf16x8* dst, int k) {
#pragma unroll
      for (int j = 0; j < 4; ++j)
        dst[j] = *(const bf16x8*)(wq + (j * 16 + l16) * 256 + k * 32 + quad * 8);
    };
    loadB(Ba, 0);
#pragma unroll
    for (int k = 0; k < 8; ++k) {
      const bf16x8* cur = (k & 1) ? Bb : Ba;
      if (k < 7) loadB((k & 1) ? Ba : Bb, k + 1);
      bf16x8 A0 = *(const bf16x8*)(&Xs[l16][k * 32 + quad * 8]);
      bf16x8 A1 = *(const bf16x8*)(&Xs[16 + l16][k * 32 + quad * 8]);
#pragma unroll
      for (int j = 0; j < 4; ++j) {
        acc[0][j] = MFMA16(A0, cur[j], acc[0][j]);
        acc[1][j] = MFMA16(A1, cur[j], acc[1][j]);
      }
    }
#pragma unroll
    for (int i = 0; i < 2; ++i)
#pragma unroll
      for (int j = 0; j < 4; ++j)
#pragma unroll
        for (int r = 0; r < 4; ++r)
          QK[i * 16 + quad * 4 + r][wave * 64 + j * 16 + l16] = (bf16_t)acc[i][j][r];
  }
  __syncthreads();

  // ---- P2: waves 0-3: per-token 8x8 head-mix softmax (e-half bursts)
  //          waves 4-7: V gemm [32x256] = X @ Wv^T (k-pipelined) ----
  float p_[8];          // probs (waves 0-3)
  floatx4 vacc[2][4];   // V acc (waves 4-7)
  if (wave < 4) {
    const int t = tid >> 3, h = tid & 7;     // 256 tasks = 32 tok x 8 heads
    bf16x8 qv[4];
#pragma unroll
    for (int u = 0; u < 4; ++u) qv[u] = *(const bf16x8*)(&QK[t][h * 32 + u * 8]);
    float qf[32];
#pragma unroll
    for (int u = 0; u < 4; ++u)
#pragma unroll
      for (int d = 0; d < 8; ++d) qf[u * 8 + d] = (float)qv[u][d];
    float sc[8];
#pragma unroll
    for (int eh = 0; eh < 2; ++eh) {
      bf16x8 kv[4][4];
#pragma unroll
      for (int e2 = 0; e2 < 4; ++e2)
#pragma unroll
        for (int u = 0; u < 4; ++u)
          kv[e2][u] = *(const bf16x8*)(&QK[t][256 + (eh * 4 + e2) * 32 + u * 8]);
#pragma unroll
      for (int e2 = 0; e2 < 4; ++e2) {
        float a = 0.f;
#pragma unroll
        for (int u = 0; u < 4; ++u)
#pragma unroll
          for (int d = 0; d < 8; ++d) a += qf[u * 8 + d] * (float)kv[e2][u][d];
        sc[eh * 4 + e2] = a;
      }
    }
    float mx = -INFINITY;
#pragma unroll
    for (int e = 0; e < 8; ++e) { sc[e] *= scale; mx = fmaxf(mx, sc[e]); }
    float sum = 0.f;
#pragma unroll
    for (int e = 0; e < 8; ++e) { p_[e] = __expf(sc[e] - mx); sum += p_[e]; }
    float rs = 1.0f / sum;
#pragma unroll
    for (int e = 0; e < 8; ++e) p_[e] *= rs;
  } else {
    const int u = wave - 4;                  // owns V cols [u*64, u*64+64)
    const bf16_t* wv = wb + (long)(512 + u * 64) * 256;
    bf16x8 Ba[4], Bb[4];
    auto loadB = [&](bf16x8* dst, int k) {
#pragma unroll
      for (int j = 0; j < 4; ++j)
        dst[j] = *(const bf16x8*)(wv + (j * 16 + l16) * 256 + k * 32 + quad * 8);
    };
#pragma unroll
    for (int i = 0; i < 2; ++i)
#pragma unroll
      for (int j = 0; j < 4; ++j) vacc[i][j] = (floatx4){0.f, 0.f, 0.f, 0.f};
    loadB(Ba, 0);
#pragma unroll
    for (int k = 0; k < 8; ++k) {
      const bf16x8* cur = (k & 1) ? Bb : Ba;
      if (k < 7) loadB((k & 1) ? Ba : Bb, k + 1);
      bf16x8 A0 = *(const bf16x8*)(&Xs[l16][k * 32 + quad * 8]);
      bf16x8 A1 = *(const bf16x8*)(&Xs[16 + l16][k * 32 + quad * 8]);
#pragma unroll
      for (int j = 0; j < 4; ++j) {
        vacc[0][j] = MFMA16(A0, cur[j], vacc[0][j]);
        vacc[1][j] = MFMA16(A1, cur[j], vacc[1][j]);
      }
    }
  }
  __syncthreads();   // q,k LDS reads done; V acc ready

  if (wave >= 4) {   // V overwrites cols 0..255 of QK
    const int u = wave - 4;
#pragma unroll
    for (int i = 0; i < 2; ++i)
#pragma unroll
      for (int j = 0; j < 4; ++j)
#pragma unroll
        for (int r = 0; r < 4; ++r)
          QK[i * 16 + quad * 4 + r][u * 64 + j * 16 + l16] = (bf16_t)vacc[i][j][r];
  }
  __syncthreads();   // V ready

  // ---- P3: PV (waves 0-3), e-half bursts; store pre ----
  if (wave < 4) {
    const int t = tid >> 3, h = tid & 7;
    float pre[32];
#pragma unroll
    for (int i = 0; i < 32; ++i) pre[i] = 0.f;
#pragma unroll
    for (int eh = 0; eh < 2; ++eh) {
      bf16x8 vv[4][4];
#pragma unroll
      for (int e2 = 0; e2 < 4; ++e2)
#pragma unroll
        for (int u = 0; u < 4; ++u)
          vv[e2][u] = *(const bf16x8*)(&QK[t][(eh * 4 + e2) * 32 + u * 8]);
#pragma unroll
      for (int e2 = 0; e2 < 4; ++e2) {
        float pe = p_[eh * 4 + e2];
#pragma unroll
        for (int u = 0; u < 4; ++u)
#pragma unroll
          for (int d = 0; d < 8; ++d) pre[u * 8 + d] += pe * (float)vv[e2][u][d];
      }
    }
    if (preb) {
      bf16_t* op = preb + (base + t) * 256 + h * 32;
#pragma unroll
      for (int u = 0; u < 4; ++u) {
        bf16_t t8[8];
#pragma unroll
        for (int d = 0; d < 8; ++d) t8[d] = (bf16_t)pre[u * 8 + d];
        *(uint4*)(op + u * 8) = *(const uint4*)t8;
      }
    } else {
      float* op = outf + (base + t) * 256 + h * 32;
#pragma unroll
      for (int u = 0; u < 8; ++u) {
        float4 f = {pre[u * 4], pre[u * 4 + 1], pre[u * 4 + 2], pre[u * 4 + 3]};
        ((float4*)op)[u] = f;
      }
    }
  }
}

// ---------------------------------------------------------------------------
// Kernel 2: per-window scramble + projection.
// flat = h*1568 + s*32 + d -> scram row flat>>8, chan flat&255 (within window).
// B preloaded in two k-halves (half 0 issued BEFORE the gather so its L2
// latency hides under staging); A double-buffered per k-step.
// Wave w owns 32 distinct output cols. In-place safe on out: all reads ->
// LDS before any store; windows own disjoint rows.
// ---------------------------------------------------------------------------
#define SC_S 264   // row stride (bf16): 528B, 16B-aligned

__global__ __launch_bounds__(512, 4) void proj_kernel(
    const bf16_t* __restrict__ wb,
    const float* __restrict__ b_proj,
    float* out,
    const bf16_t* __restrict__ preb)
{
  __shared__ __align__(16) bf16_t Sc[49][SC_S];   // 25.9 KB scrambled pre
  __shared__ int trow[49];

  const int n = blockIdx.x;              // window id 0..2047
  const int b = n >> 6, wh = (n >> 3) & 7, ww = n & 7;
  const int tid = threadIdx.x;
  const int wave = tid >> 6, lane = tid & 63, quad = lane >> 4, l16 = lane & 15;

  const bf16_t* wp = wb + 196608 + (long)(wave * 32) * 256;
  auto loadB2 = [&](bf16x8 (*dst)[2], int k0) {
#pragma unroll
    for (int kk = 0; kk < 4; ++kk)
#pragma unroll
      for (int j = 0; j < 2; ++j)
        dst[kk][j] = *(const bf16x8*)(wp + (j * 16 + l16) * 256 + (k0 + kk) * 32 + quad * 8);
  };
  // ---- B half 0 preload: issued before the gather, hides under staging ----
  bf16x8 Bh0[4][2];
  loadB2(Bh0, 0);
  float bv[2];
#pragma unroll
  for (int j = 0; j < 2; ++j) bv[j] = b_proj[wave * 32 + j * 16 + l16];

  if (tid < 49) {
    int i = tid / 7, j = tid % 7;
    trow[tid] = b * 3136 + (wh * 7 + i) * 56 + ww * 7 + j;
  }
  __syncthreads();

  // ---- stage + scramble: 49 rows x 32 chunks of 8 values ----
  if (preb) {
    for (int idx = tid; idx < 49 * 32; idx += 512) {
      int s = idx >> 5, g8 = idx & 31;
      bf16x8 v = *(const bf16x8*)(preb + (long)trow[s] * 256 + g8 * 8);
      int flat = (g8 >> 2) * 1568 + s * 32 + (g8 & 3) * 8;   // h*1568 + s*32 + d
      *(bf16x8*)(&Sc[flat >> 8][flat & 255]) = v;
    }
  } else {
    for (int idx = tid; idx < 49 * 32; idx += 512) {
      int s = idx >> 5, g8 = idx & 31;
      const float* p = out + (long)trow[s] * 256 + g8 * 8;
      float4 f0 = ((const float4*)p)[0];
      float4 f1 = ((const float4*)p)[1];
      bf16_t t8[8] = {(bf16_t)f0.x, (bf16_t)f0.y, (bf16_t)f0.z, (bf16_t)f0.w,
                      (bf16_t)f1.x, (bf16_t)f1.y, (bf16_t)f1.z, (bf16_t)f1.w};
      int flat = (g8 >> 2) * 1568 + s * 32 + (g8 & 3) * 8;
      *(uint4*)(&Sc[flat >> 8][flat & 255]) = *(const uint4*)t8;
    }
  }
  // ---- B half 1: issue before the barrier ----
  bf16x8 Bh1[4][2];
  loadB2(Bh1, 4);
  __syncthreads();

  // ---- proj gemm: out(49x256) = Sc @ Wp^T + bias; A double-buffered ----
  {
    floatx4 acc[4][2] = {};
    bf16x8 Aa[4], Ab[4];
    auto loadA = [&](bf16x8* dst, int k) {
#pragma unroll
      for (int i = 0; i < 4; ++i) {
        int mr = i * 16 + l16; if (mr > 48) mr = 48;
        dst[i] = *(const bf16x8*)(&Sc[mr][k * 32 + quad * 8]);
      }
    };
    loadA(Aa, 0);
#pragma unroll
    for (int k = 0; k < 8; ++k) {
      const bf16x8* curA = (k & 1) ? Ab : Aa;
      if (k < 7) loadA((k & 1) ? Aa : Ab, k + 1);
#pragma unroll
      for (int i = 0; i < 4; ++i)
#pragma unroll
        for (int j = 0; j < 2; ++j)
          acc[i][j] = MFMA16(curA[i], (k < 4) ? Bh0[k][j] : Bh1[k - 4][j], acc[i][j]);
    }
#pragma unroll
    for (int j = 0; j < 2; ++j) {
      int col = wave * 32 + j * 16 + l16;
#pragma unroll
      for (int i = 0; i < 4; ++i)
#pragma unroll
        for (int r = 0; r < 4; ++r) {
          int m = i * 16 + quad * 4 + r;
          if (m < 49) out[(long)trow[m] * 256 + col] = acc[i][j][r] + bv[j];
        }
    }
  }
}

// ---------------------------------------------------------------------------
extern "C" void kernel_launch(void* const* d_in, const int* in_sizes, int n_in,
                              void* d_out, int out_size, void* d_ws, size_t ws_size,
                              hipStream_t stream) {
  (void)in_sizes; (void)n_in; (void)out_size;
  const float* x      = (const float*)d_in[0];
  const float* w_qkv  = (const float*)d_in[1];
  const float* w_proj = (const float*)d_in[2];
  const float* b_proj = (const float*)d_in[3];
  float* out = (float*)d_out;
  bf16_t* wb = (bf16_t*)d_ws;   // 262144 bf16 = 512 KB

  // bf16 pre buffer (100352*256*2 = 51.4 MB) if workspace allows
  bf16_t* preb = nullptr;
  if (ws_size >= (size_t)524288 + 51380224) preb = wb + 262144;

  wconv_kernel<<<dim3(256), 256, 0, stream>>>(w_qkv, w_proj, wb);
  attn_kernel<<<dim3(3136), 512, 0, stream>>>(x, wb, out, preb);
  proj_kernel<<<dim3(2048), 512, 0, stream>>>(wb, b_proj, out, preb);
}